// Round 9
// baseline (91.236 us; speedup 1.0000x reference)
//
#include <hip/hip_runtime.h>
#include <hip/hip_bf16.h>

// Chamfer distance between two (1,16384,3) fp32 clouds via split-bf16
// augmented GEMM on the matrix cores (R7-verified exact: absmax 0).
//   A_enc[p] . B_enc[q] = |x_p|^2 + |y_q|^2 - 2 x_p.y_q = d^2(p,q)
// ONE pass over the matrix; each 64x32 MFMA tile feeds BOTH reductions:
//   row-min (cham_x): per-lane C-reg accumulators + shfl fold (R7-proven path)
//   col-min (cham_y): in-tile 64-row fold, then global atomicMin on
//   order-encoded fp32 into colmin[P] (R6-proven exact mechanism).

constexpr int P     = 16384;
constexpr int BLK   = 256;
constexpr int ROWSB = 256;           // rows per block (4 waves x 64)
constexpr int COLSB = 1024;          // cols per block
constexpr int NROWG = P / ROWSB;     // 64
constexpr int NCOLG = P / COLSB;     // 16
constexpr int ROUND = 512;           // cols staged per 16 KB LDS round
constexpr int TILES = ROUND / 32;    // 16 MFMA col-tiles per round

typedef short s8v  __attribute__((ext_vector_type(8)));
typedef float f16v __attribute__((ext_vector_type(16)));

static __device__ inline unsigned short bf16r(float f) {   // RNE fp32->bf16
    unsigned u = __float_as_uint(f);
    u = (u + 0x7FFFu + ((u >> 16) & 1u)) >> 16;
    return (unsigned short)u;
}
static __device__ inline float bf2f(unsigned short h) {
    return __uint_as_float(((unsigned)h) << 16);
}

// Order-preserving fp32 <-> uint32 (exact atomic min/max on floats; R6-proven).
static __device__ inline unsigned enc_f32(float f) {
    unsigned b = __float_as_uint(f);
    return (b & 0x80000000u) ? ~b : (b | 0x80000000u);
}
static __device__ inline float dec_f32(unsigned u) {
    unsigned b = (u & 0x80000000u) ? (u & 0x7FFFFFFFu) : ~u;
    return __uint_as_float(b);
}

// A-side encoding (rows = pc1), 16 bf16 K-slots packed as 8 uints.
static __device__ inline void encA(float a, float b, float c, unsigned e[8]) {
    const unsigned ONE = 0x3F80u;
    const float s = fmaf(a, a, fmaf(b, b, c * c));
    const unsigned short ah = bf16r(a), bh = bf16r(b), ch = bf16r(c);
    const unsigned short al = bf16r(a - bf2f(ah));
    const unsigned short bl = bf16r(b - bf2f(bh));
    const unsigned short cl = bf16r(c - bf2f(ch));
    const unsigned short sh = bf16r(s), sl = bf16r(s - bf2f(sh));
    e[0] = ah | ((unsigned)al << 16);   // k0,k1
    e[1] = bh | ((unsigned)bl << 16);   // k2,k3
    e[2] = ch | ((unsigned)cl << 16);   // k4,k5
    e[3] = ah | ((unsigned)bh << 16);   // k6,k7
    e[4] = ch | ((unsigned)sh << 16);   // k8,k9
    e[5] = sl | (ONE << 16);            // k10,k11
    e[6] = ONE;                         // k12,k13(=0)
    e[7] = 0;                           // k14,k15
}

// B-side encoding (cols = pc2; -2 folded in, exact bf16 scalings).
static __device__ inline void encB(float a, float b, float c, unsigned e[8]) {
    const unsigned ONE = 0x3F80u;
    const float s = fmaf(a, a, fmaf(b, b, c * c));
    const unsigned short ah = bf16r(a), bh = bf16r(b), ch = bf16r(c);
    const unsigned short al = bf16r(a - bf2f(ah));
    const unsigned short bl = bf16r(b - bf2f(bh));
    const unsigned short cl = bf16r(c - bf2f(ch));
    const unsigned short sh = bf16r(s), sl = bf16r(s - bf2f(sh));
    const unsigned short Ah = bf16r(-2.f * bf2f(ah)), Bh = bf16r(-2.f * bf2f(bh));
    const unsigned short Ch = bf16r(-2.f * bf2f(ch));
    const unsigned short Al = bf16r(-2.f * bf2f(al)), Bl = bf16r(-2.f * bf2f(bl));
    const unsigned short Cl = bf16r(-2.f * bf2f(cl));
    e[0] = Ah | ((unsigned)Ah << 16);   // k0,k1
    e[1] = Bh | ((unsigned)Bh << 16);   // k2,k3
    e[2] = Ch | ((unsigned)Ch << 16);   // k4,k5
    e[3] = Al | ((unsigned)Bl << 16);   // k6,k7
    e[4] = Cl | (ONE << 16);            // k8,k9
    e[5] = ONE | ((unsigned)sh << 16);  // k10,k11
    e[6] = sl;                          // k12,k13(=0)
    e[7] = 0;                           // k14,k15
}

// ---- main: one pass, dual reduction ----------------------------------------
__global__ __launch_bounds__(BLK, 4) void chamfer_mfma(
    const float* __restrict__ pc1, const float* __restrict__ pc2,
    float* __restrict__ rowpart,     // [NCOLG][P] per-row min over 1024-col slab
    unsigned* __restrict__ colmin,   // [P] encoded global col-min (init 0xFF..)
    float* __restrict__ out)
{
    if (blockIdx.x == 0 && blockIdx.y == 0 && threadIdx.x == 0)
        out[0] = 0.0f;

    __shared__ __align__(16) unsigned char ytile[ROUND * 32];  // 16 KB

    const int tid  = threadIdx.x;
    const int lane = tid & 63;
    const int wv   = tid >> 6;
    const int l31  = lane & 31;
    const int half = lane >> 5;

    // ---- A fragments: 2 strips of 32 rows per wave (rows from pc1) ----
    const int rowbase = blockIdx.x * ROWSB + wv * 64;
    s8v afrag[2];
    #pragma unroll
    for (int s = 0; s < 2; ++s) {
        const int p = rowbase + s * 32 + l31;
        unsigned e[8];
        encA(pc1[3 * p], pc1[3 * p + 1], pc1[3 * p + 2], e);
        union { uint4 i; s8v v; } lo, hi;
        lo.i = make_uint4(e[0], e[1], e[2], e[3]);
        hi.i = make_uint4(e[4], e[5], e[6], e[7]);
        afrag[s] = half ? hi.v : lo.v;
    }

    f16v acc0, acc1, Z;
    #pragma unroll
    for (int i = 0; i < 16; ++i) { acc0[i] = 3.0e38f; acc1[i] = 3.0e38f; Z[i] = 0.0f; }

    const int colbase = blockIdx.y * COLSB;
    for (int r = 0; r < COLSB / ROUND; ++r) {
        // ---- stage ROUND col-points (pc2), swizzled for lane-linear b128:
        //      tile tt, col cc, half h -> ytile[tt*1024 + h*512 + cc*16]
        __syncthreads();
        #pragma unroll
        for (int j = 0; j < ROUND / BLK; ++j) {
            const int i = tid + j * BLK;
            const int q = colbase + r * ROUND + i;
            unsigned e[8];
            encB(pc2[3 * q], pc2[3 * q + 1], pc2[3 * q + 2], e);
            const int tt = i >> 5, cc = i & 31;
            *(uint4*)(ytile + tt * 1024 +       cc * 16) = make_uint4(e[0], e[1], e[2], e[3]);
            *(uint4*)(ytile + tt * 1024 + 512 + cc * 16) = make_uint4(e[4], e[5], e[6], e[7]);
        }
        __syncthreads();

        const unsigned char* rp = ytile + lane * 16;   // conflict-free b128
        #pragma unroll 2
        for (int t = 0; t < TILES; ++t) {
            const s8v bfrag = *(const s8v*)(rp + t * 1024);
            const f16v d0 = __builtin_amdgcn_mfma_f32_32x32x16_bf16(afrag[0], bfrag, Z, 0, 0, 0);
            const f16v d1 = __builtin_amdgcn_mfma_f32_32x32x16_bf16(afrag[1], bfrag, Z, 0, 0, 0);
            // row-min: per-lane C-reg accumulate (col = lane&31 fixed per lane)
            acc0 = __builtin_elementwise_min(acc0, d0);
            acc1 = __builtin_elementwise_min(acc1, d1);
            // col-min: fold this tile's 64 rows (regs of both halves are
            // row-complementary -- proven by R7's full row coverage), then
            // exact global atomicMin on the encoded value.
            float m = fminf(d0[0], d0[1]);
            #pragma unroll
            for (int i = 2; i < 16; ++i) m = fminf(m, d0[i]);
            #pragma unroll
            for (int i = 0; i < 16; ++i) m = fminf(m, d1[i]);
            m = fminf(m, __shfl_xor(m, 32, 64));       // join the two halves
            if (lane < 32)
                atomicMin(&colmin[colbase + r * ROUND + t * 32 + l31], enc_f32(m));
        }
    }

    // ---- row epilogue: fold 32 lanes (cols) per C-reg, write rowpart ----
    // C/D layout: col=lane&31, row=(rg&3)+8*(rg>>2)+4*half (R7-verified)
    float* rowp = rowpart + (size_t)blockIdx.y * P;
    #pragma unroll
    for (int s = 0; s < 2; ++s) {
        #pragma unroll
        for (int rg = 0; rg < 16; ++rg) {
            float v = s ? acc1[rg] : acc0[rg];
            v = fminf(v, __shfl_xor(v, 1, 64));
            v = fminf(v, __shfl_xor(v, 2, 64));
            v = fminf(v, __shfl_xor(v, 4, 64));
            v = fminf(v, __shfl_xor(v, 8, 64));
            v = fminf(v, __shfl_xor(v, 16, 64));
            if (l31 == 0) {
                const int row = rowbase + s * 32 + (rg & 3) + 8 * (rg >> 2) + 4 * half;
                rowp[row] = v;
            }
        }
    }
}

// ---- reduce: fold row slabs / decode col atomics, threshold, mean, sum -----
__global__ __launch_bounds__(BLK) void chamfer_reduce(
    const float* __restrict__ rowpart, const unsigned* __restrict__ colmin,
    float* __restrict__ out)
{
    const int gid = blockIdx.x * BLK + threadIdx.x;   // 0 .. 2P-1
    const int p = gid & (P - 1);

    float m;
    if (gid < P) {                                    // cham_x: rows of pc1
        m = rowpart[p];
        #pragma unroll
        for (int s = 1; s < NCOLG; ++s) m = fminf(m, rowpart[(size_t)s * P + p]);
    } else {                                          // cham_y: cols (pc2)
        m = dec_f32(colmin[p]);
    }

    if (m >= 2.0f) m = 0.0f;                  // DIST_THD mask
    float v = m * (1.0f / (float)P);          // point mean; batch N=1

    #pragma unroll
    for (int off = 32; off > 0; off >>= 1) v += __shfl_down(v, off, 64);

    __shared__ float wsum[BLK / 64];
    const int lane = threadIdx.x & 63;
    const int wvi = threadIdx.x >> 6;
    if (lane == 0) wsum[wvi] = v;
    __syncthreads();
    if (threadIdx.x == 0) {
        float ssum = wsum[0];
        #pragma unroll
        for (int w = 1; w < BLK / 64; ++w) ssum += wsum[w];
        atomicAdd(out, ssum);
    }
}

extern "C" void kernel_launch(void* const* d_in, const int* in_sizes, int n_in,
                              void* d_out, int out_size, void* d_ws, size_t ws_size,
                              hipStream_t stream) {
    const float* pc1 = (const float*)d_in[0];
    const float* pc2 = (const float*)d_in[1];
    float* out = (float*)d_out;
    float* rowpart = (float*)d_ws;                        // [16][P] = 1 MB
    unsigned* colmin = (unsigned*)(rowpart + (size_t)NCOLG * P);  // [P] = 64 KB

    // 0xFFFFFFFF = encoded +inf-and-beyond: loses to every real d^2.
    hipMemsetAsync(colmin, 0xFF, (size_t)P * sizeof(unsigned), stream);

    dim3 grid(NROWG, NCOLG);                              // 64 x 16 = 1024 blocks
    chamfer_mfma<<<grid, BLK, 0, stream>>>(pc1, pc2, rowpart, colmin, out);
    chamfer_reduce<<<(2 * P) / BLK, BLK, 0, stream>>>(rowpart, colmin, out);
}

// Round 10
// 91.172 us; speedup vs baseline: 1.0007x; 1.0007x over previous
//
#include <hip/hip_runtime.h>
#include <hip/hip_bf16.h>

// Chamfer distance between two (1,16384,3) fp32 clouds via split-bf16
// augmented GEMM on the matrix cores (R7-verified exact: absmax 0).
//   A_enc[p] . B_enc[q] = |x_p|^2 + |y_q|^2 - 2 x_p.y_q = d^2(p,q)
// ONE pass over the matrix; each 64x32 MFMA tile feeds BOTH reductions:
//   row-min (cham_x): per-lane C-reg accumulators + shfl fold (R7-proven)
//   col-min (cham_y): per-tile tree-fold -> LDS atomicMin (encoded u32,
//   all 64 lanes; lanes L,L+32 are row-complementary so no shfl join) ->
//   ONE global atomicMin per col per block (1.05M total, 4x fewer than R9).

constexpr int P     = 16384;
constexpr int BLK   = 256;
constexpr int ROWSB = 256;           // rows per block (4 waves x 64)
constexpr int COLSB = 1024;          // cols per block
constexpr int NROWG = P / ROWSB;     // 64
constexpr int NCOLG = P / COLSB;     // 16
constexpr int ROUND = 512;           // cols staged per 16 KB LDS round
constexpr int TILES = ROUND / 32;    // 16 MFMA col-tiles per round

typedef short s8v  __attribute__((ext_vector_type(8)));
typedef float f16v __attribute__((ext_vector_type(16)));

static __device__ inline unsigned short bf16r(float f) {   // RNE fp32->bf16
    unsigned u = __float_as_uint(f);
    u = (u + 0x7FFFu + ((u >> 16) & 1u)) >> 16;
    return (unsigned short)u;
}
static __device__ inline float bf2f(unsigned short h) {
    return __uint_as_float(((unsigned)h) << 16);
}

// Order-preserving fp32 <-> uint32 (exact atomic min on floats; R6/R9-proven).
static __device__ inline unsigned enc_f32(float f) {
    unsigned b = __float_as_uint(f);
    return (b & 0x80000000u) ? ~b : (b | 0x80000000u);
}
static __device__ inline float dec_f32(unsigned u) {
    unsigned b = (u & 0x80000000u) ? (u & 0x7FFFFFFFu) : ~u;
    return __uint_as_float(b);
}

// A-side encoding (rows = pc1), 16 bf16 K-slots packed as 8 uints.
static __device__ inline void encA(float a, float b, float c, unsigned e[8]) {
    const unsigned ONE = 0x3F80u;
    const float s = fmaf(a, a, fmaf(b, b, c * c));
    const unsigned short ah = bf16r(a), bh = bf16r(b), ch = bf16r(c);
    const unsigned short al = bf16r(a - bf2f(ah));
    const unsigned short bl = bf16r(b - bf2f(bh));
    const unsigned short cl = bf16r(c - bf2f(ch));
    const unsigned short sh = bf16r(s), sl = bf16r(s - bf2f(sh));
    e[0] = ah | ((unsigned)al << 16);   // k0,k1
    e[1] = bh | ((unsigned)bl << 16);   // k2,k3
    e[2] = ch | ((unsigned)cl << 16);   // k4,k5
    e[3] = ah | ((unsigned)bh << 16);   // k6,k7
    e[4] = ch | ((unsigned)sh << 16);   // k8,k9
    e[5] = sl | (ONE << 16);            // k10,k11
    e[6] = ONE;                         // k12,k13(=0)
    e[7] = 0;                           // k14,k15
}

// B-side encoding (cols = pc2; -2 folded in, exact bf16 scalings).
static __device__ inline void encB(float a, float b, float c, unsigned e[8]) {
    const unsigned ONE = 0x3F80u;
    const float s = fmaf(a, a, fmaf(b, b, c * c));
    const unsigned short ah = bf16r(a), bh = bf16r(b), ch = bf16r(c);
    const unsigned short al = bf16r(a - bf2f(ah));
    const unsigned short bl = bf16r(b - bf2f(bh));
    const unsigned short cl = bf16r(c - bf2f(ch));
    const unsigned short sh = bf16r(s), sl = bf16r(s - bf2f(sh));
    const unsigned short Ah = bf16r(-2.f * bf2f(ah)), Bh = bf16r(-2.f * bf2f(bh));
    const unsigned short Ch = bf16r(-2.f * bf2f(ch));
    const unsigned short Al = bf16r(-2.f * bf2f(al)), Bl = bf16r(-2.f * bf2f(bl));
    const unsigned short Cl = bf16r(-2.f * bf2f(cl));
    e[0] = Ah | ((unsigned)Ah << 16);   // k0,k1
    e[1] = Bh | ((unsigned)Bh << 16);   // k2,k3
    e[2] = Ch | ((unsigned)Ch << 16);   // k4,k5
    e[3] = Al | ((unsigned)Bl << 16);   // k6,k7
    e[4] = Cl | (ONE << 16);            // k8,k9
    e[5] = ONE | ((unsigned)sh << 16);  // k10,k11
    e[6] = sl;                          // k12,k13(=0)
    e[7] = 0;                           // k14,k15
}

// ---- main: one pass, dual reduction ----------------------------------------
__global__ __launch_bounds__(BLK, 4) void chamfer_mfma(
    const float* __restrict__ pc1, const float* __restrict__ pc2,
    float* __restrict__ rowpart,     // [NCOLG][P] per-row min over 1024-col slab
    unsigned* __restrict__ colmin,   // [P] encoded global col-min (init 0xFF..)
    float* __restrict__ out)
{
    if (blockIdx.x == 0 && blockIdx.y == 0 && threadIdx.x == 0)
        out[0] = 0.0f;

    __shared__ __align__(16) unsigned char ytile[ROUND * 32];  // 16 KB
    __shared__ unsigned colacc[COLSB];                         // 4 KB, encoded

    const int tid  = threadIdx.x;
    const int lane = tid & 63;
    const int wv   = tid >> 6;
    const int l31  = lane & 31;
    const int half = lane >> 5;

    // init LDS col accumulators (encoded +inf); first r-loop barrier orders it
    #pragma unroll
    for (int i = tid; i < COLSB; i += BLK) colacc[i] = 0xFFFFFFFFu;

    // ---- A fragments: 2 strips of 32 rows per wave (rows from pc1) ----
    const int rowbase = blockIdx.x * ROWSB + wv * 64;
    s8v afrag[2];
    #pragma unroll
    for (int s = 0; s < 2; ++s) {
        const int p = rowbase + s * 32 + l31;
        unsigned e[8];
        encA(pc1[3 * p], pc1[3 * p + 1], pc1[3 * p + 2], e);
        union { uint4 i; s8v v; } lo, hi;
        lo.i = make_uint4(e[0], e[1], e[2], e[3]);
        hi.i = make_uint4(e[4], e[5], e[6], e[7]);
        afrag[s] = half ? hi.v : lo.v;
    }

    f16v acc0, acc1, Z;
    #pragma unroll
    for (int i = 0; i < 16; ++i) { acc0[i] = 3.0e38f; acc1[i] = 3.0e38f; Z[i] = 0.0f; }

    const int colbase = blockIdx.y * COLSB;
    for (int r = 0; r < COLSB / ROUND; ++r) {
        // ---- stage ROUND col-points (pc2), swizzled for lane-linear b128:
        //      tile tt, col cc, half h -> ytile[tt*1024 + h*512 + cc*16]
        __syncthreads();
        #pragma unroll
        for (int j = 0; j < ROUND / BLK; ++j) {
            const int i = tid + j * BLK;
            const int q = colbase + r * ROUND + i;
            unsigned e[8];
            encB(pc2[3 * q], pc2[3 * q + 1], pc2[3 * q + 2], e);
            const int tt = i >> 5, cc = i & 31;
            *(uint4*)(ytile + tt * 1024 +       cc * 16) = make_uint4(e[0], e[1], e[2], e[3]);
            *(uint4*)(ytile + tt * 1024 + 512 + cc * 16) = make_uint4(e[4], e[5], e[6], e[7]);
        }
        __syncthreads();

        const unsigned char* rp = ytile + lane * 16;   // conflict-free b128
        #pragma unroll 2
        for (int t = 0; t < TILES; ++t) {
            const s8v bfrag = *(const s8v*)(rp + t * 1024);
            const f16v d0 = __builtin_amdgcn_mfma_f32_32x32x16_bf16(afrag[0], bfrag, Z, 0, 0, 0);
            const f16v d1 = __builtin_amdgcn_mfma_f32_32x32x16_bf16(afrag[1], bfrag, Z, 0, 0, 0);
            // row-min: per-lane C-reg accumulate (col = lane&31 fixed per lane)
            acc0 = __builtin_elementwise_min(acc0, d0);
            acc1 = __builtin_elementwise_min(acc1, d1);
            // col-min: shallow tree fold of this lane's 8+8 rows, then LDS
            // atomicMin. Lanes L and L+32 hold complementary row-halves of the
            // SAME col, so both contribute -- no cross-lane join needed.
            const f16v dm = __builtin_elementwise_min(d0, d1);   // 16 indep
            float m0 = fminf(dm[0], dm[1]),  m1 = fminf(dm[2], dm[3]);
            float m2 = fminf(dm[4], dm[5]),  m3 = fminf(dm[6], dm[7]);
            float m4 = fminf(dm[8], dm[9]),  m5 = fminf(dm[10], dm[11]);
            float m6 = fminf(dm[12], dm[13]), m7 = fminf(dm[14], dm[15]);
            m0 = fminf(m0, m1); m2 = fminf(m2, m3);
            m4 = fminf(m4, m5); m6 = fminf(m6, m7);
            m0 = fminf(m0, m2); m4 = fminf(m4, m6);
            const float m = fminf(m0, m4);
            atomicMin(&colacc[r * ROUND + t * 32 + l31], enc_f32(m));
        }
    }

    // ---- row epilogue: fold 32 lanes (cols) per C-reg, write rowpart ----
    // C/D layout: col=lane&31, row=(rg&3)+8*(rg>>2)+4*half (R7-verified)
    float* rowp = rowpart + (size_t)blockIdx.y * P;
    #pragma unroll
    for (int s = 0; s < 2; ++s) {
        #pragma unroll
        for (int rg = 0; rg < 16; ++rg) {
            float v = s ? acc1[rg] : acc0[rg];
            v = fminf(v, __shfl_xor(v, 1, 64));
            v = fminf(v, __shfl_xor(v, 2, 64));
            v = fminf(v, __shfl_xor(v, 4, 64));
            v = fminf(v, __shfl_xor(v, 8, 64));
            v = fminf(v, __shfl_xor(v, 16, 64));
            if (l31 == 0) {
                const int row = rowbase + s * 32 + (rg & 3) + 8 * (rg >> 2) + 4 * half;
                rowp[row] = v;
            }
        }
    }

    // ---- col epilogue: ONE global atomicMin per col per block --------------
    __syncthreads();
    for (int c = tid; c < COLSB; c += BLK)
        atomicMin(&colmin[colbase + c], colacc[c]);
}

// ---- reduce: fold row slabs / decode col atomics, threshold, mean, sum -----
__global__ __launch_bounds__(BLK) void chamfer_reduce(
    const float* __restrict__ rowpart, const unsigned* __restrict__ colmin,
    float* __restrict__ out)
{
    const int gid = blockIdx.x * BLK + threadIdx.x;   // 0 .. 2P-1
    const int p = gid & (P - 1);

    float m;
    if (gid < P) {                                    // cham_x: rows of pc1
        m = rowpart[p];
        #pragma unroll
        for (int s = 1; s < NCOLG; ++s) m = fminf(m, rowpart[(size_t)s * P + p]);
    } else {                                          // cham_y: cols (pc2)
        m = dec_f32(colmin[p]);
    }

    if (m >= 2.0f) m = 0.0f;                  // DIST_THD mask
    float v = m * (1.0f / (float)P);          // point mean; batch N=1

    #pragma unroll
    for (int off = 32; off > 0; off >>= 1) v += __shfl_down(v, off, 64);

    __shared__ float wsum[BLK / 64];
    const int lane = threadIdx.x & 63;
    const int wvi = threadIdx.x >> 6;
    if (lane == 0) wsum[wvi] = v;
    __syncthreads();
    if (threadIdx.x == 0) {
        float ssum = wsum[0];
        #pragma unroll
        for (int w = 1; w < BLK / 64; ++w) ssum += wsum[w];
        atomicAdd(out, ssum);
    }
}

extern "C" void kernel_launch(void* const* d_in, const int* in_sizes, int n_in,
                              void* d_out, int out_size, void* d_ws, size_t ws_size,
                              hipStream_t stream) {
    const float* pc1 = (const float*)d_in[0];
    const float* pc2 = (const float*)d_in[1];
    float* out = (float*)d_out;
    float* rowpart = (float*)d_ws;                        // [16][P] = 1 MB
    unsigned* colmin = (unsigned*)(rowpart + (size_t)NCOLG * P);  // [P] = 64 KB

    // 0xFFFFFFFF = encoded beyond-+inf: loses to every real d^2.
    hipMemsetAsync(colmin, 0xFF, (size_t)P * sizeof(unsigned), stream);

    dim3 grid(NROWG, NCOLG);                              // 64 x 16 = 1024 blocks
    chamfer_mfma<<<grid, BLK, 0, stream>>>(pc1, pc2, rowpart, colmin, out);
    chamfer_reduce<<<(2 * P) / BLK, BLK, 0, stream>>>(rowpart, colmin, out);
}